// Round 15
// baseline (135.155 us; speedup 1.0000x reference)
//
#include <hip/hip_runtime.h>

typedef _Float16 half8  __attribute__((ext_vector_type(8)));
typedef float    f32x4  __attribute__((ext_vector_type(4)));
typedef unsigned long long u64;

constexpr int K_CODES = 1024;
constexpr int D_DIM   = 512;
constexpr float DECAY = 0.99f;
constexpr float OMD   = 0.01f;
constexpr float LO_SCALE = 2048.0f;       // 2^11: keeps lo in normal f16 range
constexpr float INV_LO   = 1.0f / 2048.0f;

constexpr int BM = 128;
constexpr int BN = 128;
constexpr int BK = 32;
constexpr int TILE = BM * BK;             // 4096 halves = 8 KB per tile
constexpr int CHUNK = 32;                 // packed entries per chunksum block

// ---------------------------------------------------------------------------
// fused: blocks [0,nA) split z_e_x into f16 hi/lo; [nA, nA+nB) per-code prep
// (cb_sqr + codebook hi/lo); [nA+nB, +nI) init minkey; [.., +nH) zero hist
// (+ the decode done-counter, re-zeroed every call — ws is never re-poisoned).
__global__ __launch_bounds__(256)
void prepsplit_kernel(const float* __restrict__ A, const float* __restrict__ cb,
                      float* __restrict__ cbsqr, u64* __restrict__ minkey,
                      int* __restrict__ hist, int* __restrict__ done,
                      _Float16* __restrict__ ah, _Float16* __restrict__ al,
                      _Float16* __restrict__ bh, _Float16* __restrict__ bl,
                      int nA, int nB, int nI) {
    int b = blockIdx.x;
    if (b < nA) {
        size_t i8 = ((size_t)b * 256 + threadIdx.x) * 8;
        f32x4 v0 = *reinterpret_cast<const f32x4*>(&A[i8]);
        f32x4 v1 = *reinterpret_cast<const f32x4*>(&A[i8 + 4]);
        half8 h, l;
        #pragma unroll
        for (int j = 0; j < 4; ++j) {
            _Float16 hh = (_Float16)v0[j];
            h[j] = hh;
            l[j] = (_Float16)((v0[j] - (float)hh) * LO_SCALE);
        }
        #pragma unroll
        for (int j = 0; j < 4; ++j) {
            _Float16 hh = (_Float16)v1[j];
            h[4 + j] = hh;
            l[4 + j] = (_Float16)((v1[j] - (float)hh) * LO_SCALE);
        }
        *reinterpret_cast<half8*>(&ah[i8]) = h;
        *reinterpret_cast<half8*>(&al[i8]) = l;
    } else if (b < nA + nB) {
        int w    = threadIdx.x >> 6;
        int lane = threadIdx.x & 63;
        int k = (b - nA) * 4 + w;
        size_t base = (size_t)k * D_DIM + lane * 8;
        f32x4 v0 = *reinterpret_cast<const f32x4*>(&cb[base]);
        f32x4 v1 = *reinterpret_cast<const f32x4*>(&cb[base + 4]);
        half8 h, l;
        float s = 0.f;
        #pragma unroll
        for (int j = 0; j < 4; ++j) {
            s += v0[j] * v0[j];
            _Float16 hh = (_Float16)v0[j];
            h[j] = hh;
            l[j] = (_Float16)((v0[j] - (float)hh) * LO_SCALE);
        }
        #pragma unroll
        for (int j = 0; j < 4; ++j) {
            s += v1[j] * v1[j];
            _Float16 hh = (_Float16)v1[j];
            h[4 + j] = hh;
            l[4 + j] = (_Float16)((v1[j] - (float)hh) * LO_SCALE);
        }
        *reinterpret_cast<half8*>(&bh[base]) = h;
        *reinterpret_cast<half8*>(&bl[base]) = l;
        #pragma unroll
        for (int off = 32; off > 0; off >>= 1) s += __shfl_down(s, off);
        if (lane == 0) cbsqr[k] = s;
    } else if (b < nA + nB + nI) {
        int i = (b - nA - nB) * 256 + threadIdx.x;
        minkey[i] = ~0ull;
    } else {
        int i = (b - nA - nB - nI) * 256 + threadIdx.x;
        hist[i] = 0;
        if (i == 0) *done = 0;
    }
}

// ---------------------------------------------------------------------------
// MFMA argmin, 16x16x32 f16, double-buffered with COUNTED vmcnt + raw
// s_barrier (r11 structure — measured best): prefetch for tile t+1 stays in
// flight across the barrier; vmcnt(8) retires only tile t's 8 loads.
// Result per row via atomicMin on a sortable (dist,idx) u64 key — min dist,
// min idx on ties == jnp.argmin first-min semantics; order-independent.
__global__ __launch_bounds__(256, 2)
void argmin_mfma(const _Float16* __restrict__ Ah,    // [N, D]
                 const _Float16* __restrict__ Al,
                 const _Float16* __restrict__ Bh,    // [K, D]
                 const _Float16* __restrict__ Bl,
                 const float* __restrict__ cbsqr,    // [K]
                 u64* __restrict__ minkey) {         // [N]
    __shared__ _Float16 Ahs[2][TILE];     // 8 KiB per tile per buffer
    __shared__ _Float16 Als[2][TILE];
    __shared__ _Float16 Bhs[2][TILE];
    __shared__ _Float16 Bls[2][TILE];
    __shared__ float    sv[2][BM];        // cross-wave argmin combine
    __shared__ int      si[2][BM];

    const int tid  = threadIdx.x;
    const int lane = tid & 63;
    const int wid  = tid >> 6;
    const int wr = wid >> 1, wc = wid & 1;     // wave -> 64x64 quadrant
    const int lq = lane >> 4;                  // k-chunk select
    const int lr = lane & 15;                  // row/col within fragment

    const int row0  = blockIdx.x * BM;
    const int cbase = blockIdx.y * BN;

    f32x4 acc_h[4][4], acc_c[4][4];
    #pragma unroll
    for (int m = 0; m < 4; ++m)
        #pragma unroll
        for (int n = 0; n < 4; ++n) {
            acc_h[m][n] = f32x4{0.f, 0.f, 0.f, 0.f};
            acc_c[m][n] = f32x4{0.f, 0.f, 0.f, 0.f};
        }

    // stage one K-tile (8 global_load_lds per thread): rows are 64B = four
    // 16B chunks; chunk c of row r goes at pos c ^ ((r^(r>>2))&3)
    // (inverse-swizzled source, linear dest as global_load_lds requires)
    auto stage = [&](int buf, int d0) {
        #pragma unroll
        for (int it = 0; it < 2; ++it) {
            int p = it * 4096 + wid * 1024 + lane * 16;    // dest byte pos
            int row  = p >> 6;
            int cpos = (p >> 4) & 3;
            int sc   = cpos ^ ((row ^ (row >> 2)) & 3);
            size_t aoff = (size_t)(row0 + row) * D_DIM + d0 + sc * 8;
            size_t boff = (size_t)(cbase + row) * D_DIM + d0 + sc * 8;
            int dst = it * 2048 + wid * 512;               // in halves
            __builtin_amdgcn_global_load_lds(
                (const __attribute__((address_space(1))) void*)(Ah + aoff),
                (__attribute__((address_space(3))) void*)(&Ahs[buf][dst]), 16, 0, 0);
            __builtin_amdgcn_global_load_lds(
                (const __attribute__((address_space(1))) void*)(Al + aoff),
                (__attribute__((address_space(3))) void*)(&Als[buf][dst]), 16, 0, 0);
            __builtin_amdgcn_global_load_lds(
                (const __attribute__((address_space(1))) void*)(Bh + boff),
                (__attribute__((address_space(3))) void*)(&Bhs[buf][dst]), 16, 0, 0);
            __builtin_amdgcn_global_load_lds(
                (const __attribute__((address_space(1))) void*)(Bl + boff),
                (__attribute__((address_space(3))) void*)(&Bls[buf][dst]), 16, 0, 0);
        }
    };

    stage(0, 0);
    __syncthreads();   // prologue: full drain once, tile 0 resident

    constexpr int NSTEP = D_DIM / BK;   // 16
    for (int t = 0; t < NSTEP; ++t) {
        const int buf = t & 1;
        if (t + 1 < NSTEP) {
            stage(buf ^ 1, (t + 1) * BK);   // 8 loads stay in flight
            asm volatile("s_waitcnt vmcnt(8)" ::: "memory");  // cur tile's 8 done
        } else {
            asm volatile("s_waitcnt vmcnt(0)" ::: "memory");  // final tile drain
        }
        __builtin_amdgcn_sched_barrier(0);     // rule #18: pin the wait
        __builtin_amdgcn_s_barrier();          // all waves' cur-tile loads retired

        half8 bh[4], bl[4];
        #pragma unroll
        for (int n = 0; n < 4; ++n) {
            int rB  = wc * 64 + n * 16 + lr;
            int pos = lq ^ ((rB ^ (rB >> 2)) & 3);
            bh[n] = *reinterpret_cast<const half8*>(&Bhs[buf][rB * 32 + pos * 8]);
            bl[n] = *reinterpret_cast<const half8*>(&Bls[buf][rB * 32 + pos * 8]);
        }
        #pragma unroll
        for (int m = 0; m < 4; ++m) {
            int rA  = wr * 64 + m * 16 + lr;
            int pos = lq ^ ((rA ^ (rA >> 2)) & 3);
            half8 ah = *reinterpret_cast<const half8*>(&Ahs[buf][rA * 32 + pos * 8]);
            half8 al = *reinterpret_cast<const half8*>(&Als[buf][rA * 32 + pos * 8]);
            #pragma unroll
            for (int n = 0; n < 4; ++n) {
                acc_h[m][n] = __builtin_amdgcn_mfma_f32_16x16x32_f16(ah, bh[n], acc_h[m][n], 0, 0, 0);
                acc_c[m][n] = __builtin_amdgcn_mfma_f32_16x16x32_f16(ah, bl[n], acc_c[m][n], 0, 0, 0);
                acc_c[m][n] = __builtin_amdgcn_mfma_f32_16x16x32_f16(al, bh[n], acc_c[m][n], 0, 0, 0);
            }
        }
        __builtin_amdgcn_s_barrier();   // all reads of buf done before restage
    }

    // fused argmin epilogue. C/D layout: col = lane&15, row = lq*4 + reg
    float cs[4];
    #pragma unroll
    for (int n = 0; n < 4; ++n) cs[n] = cbsqr[cbase + wc * 64 + n * 16 + lr];

    #pragma unroll
    for (int m = 0; m < 4; ++m) {
        #pragma unroll
        for (int q = 0; q < 4; ++q) {
            float bv = 3.4e38f;
            int   bi = 0;
            #pragma unroll
            for (int n = 0; n < 4; ++n) {    // ascending col: strict '<' = first min
                float d = cs[n] - 2.0f * acc_h[m][n][q] - (2.0f * INV_LO) * acc_c[m][n][q];
                int   c = cbase + wc * 64 + n * 16 + lr;
                if (d < bv) { bv = d; bi = c; }
            }
            #pragma unroll
            for (int off = 1; off < 16; off <<= 1) {
                float v2 = __shfl_xor(bv, off);
                int   i2 = __shfl_xor(bi, off);
                if (v2 < bv || (v2 == bv && i2 < bi)) { bv = v2; bi = i2; }
            }
            if (lr == 0) {
                int prow = wr * 64 + m * 16 + lq * 4 + q;   // 0..127 in block
                sv[wc][prow] = bv;
                si[wc][prow] = bi;
            }
        }
    }
    __syncthreads();
    if (tid < BM) {
        float v0 = sv[0][tid], v1 = sv[1][tid];
        int   i0 = si[0][tid], i1 = si[1][tid];
        float bv = (v1 < v0) ? v1 : v0;   // tie keeps wc=0 = smaller col
        int   bi = (v1 < v0) ? i1 : i0;
        // sortable float key: order-preserving u32, then (dist,idx) lexicographic
        unsigned u = __float_as_uint(bv);
        unsigned k32 = ((int)u >= 0) ? (u ^ 0x80000000u) : ~u;
        u64 key = ((u64)k32 << 32) | (unsigned)bi;
        atomicMin(&minkey[row0 + tid], key);
    }
}

// ---------------------------------------------------------------------------
// parallel decode + fused scan: per-block LDS histogram of minkey codes ->
// global hist (device-scope atomics); LAST block (done-counter) performs the
// exclusive scan into counts/offs/cursor. One launch instead of two.
__global__ __launch_bounds__(256)
void decode_kernel(const u64* __restrict__ minkey, int* __restrict__ hist,
                   int* __restrict__ done, float* __restrict__ counts,
                   int* __restrict__ offs, int* __restrict__ cursor, int N) {
    __shared__ int lh[K_CODES];
    __shared__ int part[256];
    __shared__ int isLast;
    int t = threadIdx.x;
    #pragma unroll
    for (int j = 0; j < K_CODES / 256; ++j) lh[t + j * 256] = 0;
    __syncthreads();
    int i = blockIdx.x * 256 + t;
    if (i < N) {
        int idx = (int)(unsigned)(minkey[i] & 0xFFFFFFFFull);
        atomicAdd(&lh[idx], 1);
    }
    __syncthreads();
    #pragma unroll
    for (int j = 0; j < K_CODES / 256; ++j) {
        int v = lh[t + j * 256];
        if (v) atomicAdd(&hist[t + j * 256], v);
    }
    __threadfence();                      // hist atomics visible device-wide
    if (t == 0) {
        int v = atomicAdd(done, 1);
        isLast = (v == (int)gridDim.x - 1);
    }
    __syncthreads();
    if (!isLast) return;

    // last block: exclusive scan of hist -> counts/offs/cursor
    int c[4], s = 0;
    #pragma unroll
    for (int j = 0; j < 4; ++j) { c[j] = hist[t * 4 + j]; s += c[j]; }
    part[t] = s;
    __syncthreads();
    for (int off = 1; off < 256; off <<= 1) {
        int v   = part[t];
        int add = (t >= off) ? part[t - off] : 0;
        __syncthreads();
        part[t] = v + add;
        __syncthreads();
    }
    int run = part[t] - s;
    #pragma unroll
    for (int j = 0; j < 4; ++j) {
        offs[t * 4 + j]   = run;
        cursor[t * 4 + j] = run;
        counts[t * 4 + j] = (float)c[j];
        run += c[j];
    }
    if (t == 255) offs[K_CODES] = part[255];
}

// ---------------------------------------------------------------------------
// fused: blocks [0,nzero) zero dw; blocks [nzero,..) bucket rows by code
// (decoded from minkey), packed entries (code<<16)|row
__global__ __launch_bounds__(256)
void zeroscatter_kernel(const u64* __restrict__ minkey, int* __restrict__ cursor,
                        int* __restrict__ packed, float4* __restrict__ dw,
                        int N, int nzero) {
    int b = blockIdx.x;
    if (b < nzero) {
        dw[b * 256 + threadIdx.x] = make_float4(0.f, 0.f, 0.f, 0.f);
    } else {
        int r = (b - nzero) * 256 + threadIdx.x;
        if (r >= N) return;
        int k = (int)(unsigned)(minkey[r] & 0xFFFFFFFFull);
        int pos = atomicAdd(&cursor[k], 1);
        packed[pos] = (k << 16) | r;
    }
}

// ---------------------------------------------------------------------------
// balanced segmented sum: block b owns packed[b*CHUNK .. b*CHUNK+CHUNK).
__global__ __launch_bounds__(128)
void chunksum_kernel(const float* __restrict__ flat, const int* __restrict__ packed,
                     float* __restrict__ dw, int N) {
    __shared__ int ent[CHUNK + 1];
    const int t = threadIdx.x;
    const int base = blockIdx.x * CHUNK;
    const int cnt = min(CHUNK, N - base);
    if (t < cnt) ent[t] = packed[base + t];
    if (t == cnt) ent[t] = -1;            // sentinel: forces flush at end
    __syncthreads();

    f32x4 acc = {0.f, 0.f, 0.f, 0.f};
    for (int i0 = 0; i0 < cnt; i0 += 8) {
        const int m = min(8, cnt - i0);
        f32x4 v[8];
        #pragma unroll
        for (int j = 0; j < 8; ++j) {
            if (j < m) {
                int r = ent[i0 + j] & 0xFFFF;
                v[j] = *reinterpret_cast<const f32x4*>(&flat[(size_t)r * D_DIM + t * 4]);
            }
        }
        #pragma unroll
        for (int j = 0; j < 8; ++j) {
            if (j < m) {
                acc[0] += v[j][0]; acc[1] += v[j][1];
                acc[2] += v[j][2]; acc[3] += v[j][3];
                int k = ent[i0 + j] >> 16;
                if ((ent[i0 + j + 1] >> 16) != k) {   // uniform branch
                    float* p = &dw[(size_t)k * D_DIM + t * 4];
                    atomicAdd(p + 0, acc[0]);
                    atomicAdd(p + 1, acc[1]);
                    atomicAdd(p + 2, acc[2]);
                    atomicAdd(p + 3, acc[3]);
                    acc = f32x4{0.f, 0.f, 0.f, 0.f};
                }
            }
        }
    }
}

// ---------------------------------------------------------------------------
// fused tail: blocks [0,nfin) = finalize per code (new_ema_w/new_emb/new_count);
// blocks [nfin,..) = per-row gather (code from minkey), recomputing nw/nc
// from dw directly.
__global__ __launch_bounds__(256)
void tail_kernel(const float* __restrict__ codebook,
                 const float* __restrict__ ema_count, const float* __restrict__ ema_w,
                 const float* __restrict__ counts, const float* __restrict__ dw,
                 const u64* __restrict__ minkey,
                 float* __restrict__ new_emb, float* __restrict__ new_count,
                 float* __restrict__ new_ema_w,
                 float* __restrict__ zq, float* __restrict__ zqb, int nfin) {
    int b = blockIdx.x;
    if (b < nfin) {
        int gid = b * 256 + threadIdx.x;   // K*D/4 domain
        int k = gid >> 7;
        int d = (gid & 127) * 4;
        float nc = DECAY * ema_count[k] + OMD * counts[k];
        size_t off = (size_t)k * D_DIM + d;
        f32x4 w  = *reinterpret_cast<const f32x4*>(&ema_w[off]);
        f32x4 dv = *reinterpret_cast<const f32x4*>(&dw[off]);
        f32x4 nw, ne;
        float inv = 1.0f / nc;
        #pragma unroll
        for (int j = 0; j < 4; ++j) {
            nw[j] = DECAY * w[j] + OMD * dv[j];
            ne[j] = nw[j] * inv;
        }
        *reinterpret_cast<f32x4*>(&new_ema_w[off]) = nw;
        *reinterpret_cast<f32x4*>(&new_emb[off])   = ne;
        if ((gid & 127) == 0) new_count[k] = nc;
    } else {
        int gid = (b - nfin) * 256 + threadIdx.x;   // N*D/4 domain
        int r = gid >> 7;
        int d = (gid & 127) * 4;
        int k = (int)(unsigned)(minkey[r] & 0xFFFFFFFFull);
        size_t src = (size_t)k * D_DIM + d;
        size_t dst = (size_t)r * D_DIM + d;
        float nc = DECAY * ema_count[k] + OMD * counts[k];
        float inv = 1.0f / nc;
        f32x4 w  = *reinterpret_cast<const f32x4*>(&ema_w[src]);
        f32x4 dv = *reinterpret_cast<const f32x4*>(&dw[src]);
        f32x4 zb;
        #pragma unroll
        for (int j = 0; j < 4; ++j) zb[j] = (DECAY * w[j] + OMD * dv[j]) * inv;
        *reinterpret_cast<f32x4*>(&zqb[dst]) = zb;
        *reinterpret_cast<f32x4*>(&zq[dst])  = *reinterpret_cast<const f32x4*>(&codebook[src]);
    }
}

// ---------------------------------------------------------------------------
extern "C" void kernel_launch(void* const* d_in, const int* in_sizes, int n_in,
                              void* d_out, int out_size, void* d_ws, size_t ws_size,
                              hipStream_t stream) {
    const float* z_e_x     = (const float*)d_in[0];
    const float* codebook  = (const float*)d_in[1];
    const float* ema_count = (const float*)d_in[2];
    const float* ema_w     = (const float*)d_in[3];

    const int N = in_sizes[0] / D_DIM;   // 16384

    float* out = (float*)d_out;
    float* z_q_x     = out;
    float* z_q_x_bar = z_q_x + (size_t)N * D_DIM;
    float* new_emb   = z_q_x_bar + (size_t)N * D_DIM;
    float* new_count = new_emb + (size_t)K_CODES * D_DIM;
    float* new_ema_w = new_count + K_CODES;

    // Ah/Al (N*D f16 each = 32 MB total) live in the z_q_x_bar output region:
    // exactly N*D*4 bytes, not written until the final tail gather.
    _Float16* Ahp = (_Float16*)z_q_x_bar;
    _Float16* Alp = Ahp + (size_t)N * D_DIM;

    // workspace: cbsqr | minkey | counts | hist | done | bh/bl(=dw) | offs | cursor | packed
    char* ws = (char*)d_ws;
    float* cbsqr   = (float*)ws;                                 // K floats (4KB)
    u64*   minkey  = (u64*)(cbsqr + K_CODES);                    // N u64 (8B-aligned)
    float* counts  = (float*)(minkey + N);                       // K
    int*   hist    = (int*)(counts + K_CODES);                   // K ints
    int*   done    = hist + K_CODES;                             // 1 int (+pad)
    _Float16* bh   = (_Float16*)(done + 4);                      // K*D f16
    _Float16* bl   = bh + (size_t)K_CODES * D_DIM;               // K*D f16
    float* dw      = (float*)bh;                                 // K*D f32 (alias)
    int*   offs    = (int*)(bl + (size_t)K_CODES * D_DIM);       // K+1 ints
    int*   cursor  = offs + K_CODES + 1;                         // K ints
    int*   packed  = cursor + K_CODES;                           // N ints

    const int nA = (N * D_DIM / 8) / 256;        // splitA blocks (4096)
    const int nB = K_CODES / 4;                  // B-prep blocks (256)
    const int nI = N / 256;                      // minkey-init blocks (64)
    const int nH = K_CODES / 256;                // hist-zero blocks (4)
    prepsplit_kernel<<<nA + nB + nI + nH, 256, 0, stream>>>(
        z_e_x, codebook, cbsqr, minkey, hist, done, Ahp, Alp, bh, bl, nA, nB, nI);

    dim3 g_argmin(N / BM, K_CODES / BN);   // (128, 8)
    argmin_mfma<<<g_argmin, 256, 0, stream>>>(Ahp, Alp, bh, bl, cbsqr, minkey);

    decode_kernel<<<(N + 255) / 256, 256, 0, stream>>>(
        minkey, hist, done, counts, offs, cursor, N);

    const int nzero = (K_CODES * D_DIM / 4) / 256;   // 512 zero blocks
    zeroscatter_kernel<<<nzero + (N + 255) / 256, 256, 0, stream>>>(
        minkey, cursor, packed, (float4*)dw, N, nzero);

    chunksum_kernel<<<(N + CHUNK - 1) / CHUNK, 128, 0, stream>>>(z_e_x, packed, dw, N);

    const int nfin = (K_CODES * D_DIM / 4) / 256;    // 512 finalize blocks
    tail_kernel<<<nfin + (N * D_DIM / 4) / 256, 256, 0, stream>>>(
        codebook, ema_count, ema_w, counts, dw, minkey,
        new_emb, new_count, new_ema_w, z_q_x, z_q_x_bar, nfin);
}

// Round 16
// 127.665 us; speedup vs baseline: 1.0587x; 1.0587x over previous
//
#include <hip/hip_runtime.h>

typedef _Float16 half8  __attribute__((ext_vector_type(8)));
typedef float    f32x4  __attribute__((ext_vector_type(4)));
typedef unsigned long long u64;

constexpr int K_CODES = 1024;
constexpr int D_DIM   = 512;
constexpr float DECAY = 0.99f;
constexpr float OMD   = 0.01f;
constexpr float LO_SCALE = 2048.0f;       // 2^11: keeps lo in normal f16 range
constexpr float INV_LO   = 1.0f / 2048.0f;

constexpr int BM = 128;
constexpr int BN = 128;
constexpr int BK = 32;
constexpr int TILE = BM * BK;             // 4096 halves = 8 KB per tile
constexpr int CHUNK = 32;                 // packed entries per chunksum block

// ---------------------------------------------------------------------------
// fused: blocks [0,nA) split z_e_x into f16 hi/lo; [nA, nA+nB) per-code prep
// (cb_sqr + codebook hi/lo); [nA+nB, nA+nB+nI) init minkey; [.., +4) zero hist.
__global__ __launch_bounds__(256)
void prepsplit_kernel(const float* __restrict__ A, const float* __restrict__ cb,
                      float* __restrict__ cbsqr, u64* __restrict__ minkey,
                      int* __restrict__ hist,
                      _Float16* __restrict__ ah, _Float16* __restrict__ al,
                      _Float16* __restrict__ bh, _Float16* __restrict__ bl,
                      int nA, int nB, int nI) {
    int b = blockIdx.x;
    if (b < nA) {
        size_t i8 = ((size_t)b * 256 + threadIdx.x) * 8;
        f32x4 v0 = *reinterpret_cast<const f32x4*>(&A[i8]);
        f32x4 v1 = *reinterpret_cast<const f32x4*>(&A[i8 + 4]);
        half8 h, l;
        #pragma unroll
        for (int j = 0; j < 4; ++j) {
            _Float16 hh = (_Float16)v0[j];
            h[j] = hh;
            l[j] = (_Float16)((v0[j] - (float)hh) * LO_SCALE);
        }
        #pragma unroll
        for (int j = 0; j < 4; ++j) {
            _Float16 hh = (_Float16)v1[j];
            h[4 + j] = hh;
            l[4 + j] = (_Float16)((v1[j] - (float)hh) * LO_SCALE);
        }
        *reinterpret_cast<half8*>(&ah[i8]) = h;
        *reinterpret_cast<half8*>(&al[i8]) = l;
    } else if (b < nA + nB) {
        int w    = threadIdx.x >> 6;
        int lane = threadIdx.x & 63;
        int k = (b - nA) * 4 + w;
        size_t base = (size_t)k * D_DIM + lane * 8;
        f32x4 v0 = *reinterpret_cast<const f32x4*>(&cb[base]);
        f32x4 v1 = *reinterpret_cast<const f32x4*>(&cb[base + 4]);
        half8 h, l;
        float s = 0.f;
        #pragma unroll
        for (int j = 0; j < 4; ++j) {
            s += v0[j] * v0[j];
            _Float16 hh = (_Float16)v0[j];
            h[j] = hh;
            l[j] = (_Float16)((v0[j] - (float)hh) * LO_SCALE);
        }
        #pragma unroll
        for (int j = 0; j < 4; ++j) {
            s += v1[j] * v1[j];
            _Float16 hh = (_Float16)v1[j];
            h[4 + j] = hh;
            l[4 + j] = (_Float16)((v1[j] - (float)hh) * LO_SCALE);
        }
        *reinterpret_cast<half8*>(&bh[base]) = h;
        *reinterpret_cast<half8*>(&bl[base]) = l;
        #pragma unroll
        for (int off = 32; off > 0; off >>= 1) s += __shfl_down(s, off);
        if (lane == 0) cbsqr[k] = s;
    } else if (b < nA + nB + nI) {
        int i = (b - nA - nB) * 256 + threadIdx.x;
        minkey[i] = ~0ull;
    } else {
        hist[(b - nA - nB - nI) * 256 + threadIdx.x] = 0;
    }
}

// ---------------------------------------------------------------------------
// MFMA argmin, 16x16x32 f16, double-buffered with COUNTED vmcnt + raw
// s_barrier (r11 structure — measured best): prefetch for tile t+1 stays in
// flight across the barrier; vmcnt(8) retires only tile t's 8 loads.
// Result per row via atomicMin on a sortable (dist,idx) u64 key — min dist,
// min idx on ties == jnp.argmin first-min semantics; order-independent.
__global__ __launch_bounds__(256, 2)
void argmin_mfma(const _Float16* __restrict__ Ah,    // [N, D]
                 const _Float16* __restrict__ Al,
                 const _Float16* __restrict__ Bh,    // [K, D]
                 const _Float16* __restrict__ Bl,
                 const float* __restrict__ cbsqr,    // [K]
                 u64* __restrict__ minkey) {         // [N]
    __shared__ _Float16 Ahs[2][TILE];     // 8 KiB per tile per buffer
    __shared__ _Float16 Als[2][TILE];
    __shared__ _Float16 Bhs[2][TILE];
    __shared__ _Float16 Bls[2][TILE];
    __shared__ float    sv[2][BM];        // cross-wave argmin combine
    __shared__ int      si[2][BM];

    const int tid  = threadIdx.x;
    const int lane = tid & 63;
    const int wid  = tid >> 6;
    const int wr = wid >> 1, wc = wid & 1;     // wave -> 64x64 quadrant
    const int lq = lane >> 4;                  // k-chunk select
    const int lr = lane & 15;                  // row/col within fragment

    const int row0  = blockIdx.x * BM;
    const int cbase = blockIdx.y * BN;

    f32x4 acc_h[4][4], acc_c[4][4];
    #pragma unroll
    for (int m = 0; m < 4; ++m)
        #pragma unroll
        for (int n = 0; n < 4; ++n) {
            acc_h[m][n] = f32x4{0.f, 0.f, 0.f, 0.f};
            acc_c[m][n] = f32x4{0.f, 0.f, 0.f, 0.f};
        }

    // stage one K-tile (8 global_load_lds per thread): rows are 64B = four
    // 16B chunks; chunk c of row r goes at pos c ^ ((r^(r>>2))&3)
    // (inverse-swizzled source, linear dest as global_load_lds requires)
    auto stage = [&](int buf, int d0) {
        #pragma unroll
        for (int it = 0; it < 2; ++it) {
            int p = it * 4096 + wid * 1024 + lane * 16;    // dest byte pos
            int row  = p >> 6;
            int cpos = (p >> 4) & 3;
            int sc   = cpos ^ ((row ^ (row >> 2)) & 3);
            size_t aoff = (size_t)(row0 + row) * D_DIM + d0 + sc * 8;
            size_t boff = (size_t)(cbase + row) * D_DIM + d0 + sc * 8;
            int dst = it * 2048 + wid * 512;               // in halves
            __builtin_amdgcn_global_load_lds(
                (const __attribute__((address_space(1))) void*)(Ah + aoff),
                (__attribute__((address_space(3))) void*)(&Ahs[buf][dst]), 16, 0, 0);
            __builtin_amdgcn_global_load_lds(
                (const __attribute__((address_space(1))) void*)(Al + aoff),
                (__attribute__((address_space(3))) void*)(&Als[buf][dst]), 16, 0, 0);
            __builtin_amdgcn_global_load_lds(
                (const __attribute__((address_space(1))) void*)(Bh + boff),
                (__attribute__((address_space(3))) void*)(&Bhs[buf][dst]), 16, 0, 0);
            __builtin_amdgcn_global_load_lds(
                (const __attribute__((address_space(1))) void*)(Bl + boff),
                (__attribute__((address_space(3))) void*)(&Bls[buf][dst]), 16, 0, 0);
        }
    };

    stage(0, 0);
    __syncthreads();   // prologue: full drain once, tile 0 resident

    constexpr int NSTEP = D_DIM / BK;   // 16
    for (int t = 0; t < NSTEP; ++t) {
        const int buf = t & 1;
        if (t + 1 < NSTEP) {
            stage(buf ^ 1, (t + 1) * BK);   // 8 loads stay in flight
            asm volatile("s_waitcnt vmcnt(8)" ::: "memory");  // cur tile's 8 done
        } else {
            asm volatile("s_waitcnt vmcnt(0)" ::: "memory");  // final tile drain
        }
        __builtin_amdgcn_sched_barrier(0);     // rule #18: pin the wait
        __builtin_amdgcn_s_barrier();          // all waves' cur-tile loads retired

        half8 bh[4], bl[4];
        #pragma unroll
        for (int n = 0; n < 4; ++n) {
            int rB  = wc * 64 + n * 16 + lr;
            int pos = lq ^ ((rB ^ (rB >> 2)) & 3);
            bh[n] = *reinterpret_cast<const half8*>(&Bhs[buf][rB * 32 + pos * 8]);
            bl[n] = *reinterpret_cast<const half8*>(&Bls[buf][rB * 32 + pos * 8]);
        }
        #pragma unroll
        for (int m = 0; m < 4; ++m) {
            int rA  = wr * 64 + m * 16 + lr;
            int pos = lq ^ ((rA ^ (rA >> 2)) & 3);
            half8 ah = *reinterpret_cast<const half8*>(&Ahs[buf][rA * 32 + pos * 8]);
            half8 al = *reinterpret_cast<const half8*>(&Als[buf][rA * 32 + pos * 8]);
            #pragma unroll
            for (int n = 0; n < 4; ++n) {
                acc_h[m][n] = __builtin_amdgcn_mfma_f32_16x16x32_f16(ah, bh[n], acc_h[m][n], 0, 0, 0);
                acc_c[m][n] = __builtin_amdgcn_mfma_f32_16x16x32_f16(ah, bl[n], acc_c[m][n], 0, 0, 0);
                acc_c[m][n] = __builtin_amdgcn_mfma_f32_16x16x32_f16(al, bh[n], acc_c[m][n], 0, 0, 0);
            }
        }
        __builtin_amdgcn_s_barrier();   // all reads of buf done before restage
    }

    // fused argmin epilogue. C/D layout: col = lane&15, row = lq*4 + reg
    float cs[4];
    #pragma unroll
    for (int n = 0; n < 4; ++n) cs[n] = cbsqr[cbase + wc * 64 + n * 16 + lr];

    #pragma unroll
    for (int m = 0; m < 4; ++m) {
        #pragma unroll
        for (int q = 0; q < 4; ++q) {
            float bv = 3.4e38f;
            int   bi = 0;
            #pragma unroll
            for (int n = 0; n < 4; ++n) {    // ascending col: strict '<' = first min
                float d = cs[n] - 2.0f * acc_h[m][n][q] - (2.0f * INV_LO) * acc_c[m][n][q];
                int   c = cbase + wc * 64 + n * 16 + lr;
                if (d < bv) { bv = d; bi = c; }
            }
            #pragma unroll
            for (int off = 1; off < 16; off <<= 1) {
                float v2 = __shfl_xor(bv, off);
                int   i2 = __shfl_xor(bi, off);
                if (v2 < bv || (v2 == bv && i2 < bi)) { bv = v2; bi = i2; }
            }
            if (lr == 0) {
                int prow = wr * 64 + m * 16 + lq * 4 + q;   // 0..127 in block
                sv[wc][prow] = bv;
                si[wc][prow] = bi;
            }
        }
    }
    __syncthreads();
    if (tid < BM) {
        float v0 = sv[0][tid], v1 = sv[1][tid];
        int   i0 = si[0][tid], i1 = si[1][tid];
        float bv = (v1 < v0) ? v1 : v0;   // tie keeps wc=0 = smaller col
        int   bi = (v1 < v0) ? i1 : i0;
        // sortable float key: order-preserving u32, then (dist,idx) lexicographic
        unsigned u = __float_as_uint(bv);
        unsigned k32 = ((int)u >= 0) ? (u ^ 0x80000000u) : ~u;
        u64 key = ((u64)k32 << 32) | (unsigned)bi;
        atomicMin(&minkey[row0 + tid], key);
    }
}

// ---------------------------------------------------------------------------
// parallel decode: minkey -> indices, per-block LDS histogram -> global hist
__global__ __launch_bounds__(256)
void decode_kernel(const u64* __restrict__ minkey, int* __restrict__ indices,
                   int* __restrict__ hist, int N) {
    __shared__ int lh[K_CODES];
    int t = threadIdx.x;
    #pragma unroll
    for (int j = 0; j < K_CODES / 256; ++j) lh[t + j * 256] = 0;
    __syncthreads();
    int i = blockIdx.x * 256 + t;
    if (i < N) {
        int idx = (int)(unsigned)(minkey[i] & 0xFFFFFFFFull);
        indices[i] = idx;
        atomicAdd(&lh[idx], 1);
    }
    __syncthreads();
    #pragma unroll
    for (int j = 0; j < K_CODES / 256; ++j) {
        int v = lh[t + j * 256];
        if (v) atomicAdd(&hist[t + j * 256], v);
    }
}

// ---------------------------------------------------------------------------
// single block over K only: hist -> counts(float), exclusive scan -> offs+cursor
__global__ __launch_bounds__(256)
void scan_kernel(const int* __restrict__ hist, float* __restrict__ counts,
                 int* __restrict__ offs, int* __restrict__ cursor) {
    __shared__ int part[256];
    int t = threadIdx.x;
    int c[4], s = 0;
    #pragma unroll
    for (int j = 0; j < 4; ++j) { c[j] = hist[t * 4 + j]; s += c[j]; }
    part[t] = s;
    __syncthreads();
    for (int off = 1; off < 256; off <<= 1) {
        int v   = part[t];
        int add = (t >= off) ? part[t - off] : 0;
        __syncthreads();
        part[t] = v + add;
        __syncthreads();
    }
    int run = part[t] - s;
    #pragma unroll
    for (int j = 0; j < 4; ++j) {
        offs[t * 4 + j]   = run;
        cursor[t * 4 + j] = run;
        counts[t * 4 + j] = (float)c[j];
        run += c[j];
    }
    if (t == 255) offs[K_CODES] = part[255];
}

// ---------------------------------------------------------------------------
// fused: blocks [0,nzero) zero dw; blocks [nzero,..) bucket rows by code,
// packed entries (code<<16)|row
__global__ __launch_bounds__(256)
void zeroscatter_kernel(const int* __restrict__ indices, int* __restrict__ cursor,
                        int* __restrict__ packed, float4* __restrict__ dw,
                        int N, int nzero) {
    int b = blockIdx.x;
    if (b < nzero) {
        dw[b * 256 + threadIdx.x] = make_float4(0.f, 0.f, 0.f, 0.f);
    } else {
        int r = (b - nzero) * 256 + threadIdx.x;
        if (r >= N) return;
        int k = indices[r];
        int pos = atomicAdd(&cursor[k], 1);
        packed[pos] = (k << 16) | r;
    }
}

// ---------------------------------------------------------------------------
// balanced segmented sum: block b owns packed[b*CHUNK .. b*CHUNK+CHUNK).
__global__ __launch_bounds__(128)
void chunksum_kernel(const float* __restrict__ flat, const int* __restrict__ packed,
                     float* __restrict__ dw, int N) {
    __shared__ int ent[CHUNK + 1];
    const int t = threadIdx.x;
    const int base = blockIdx.x * CHUNK;
    const int cnt = min(CHUNK, N - base);
    if (t < cnt) ent[t] = packed[base + t];
    if (t == cnt) ent[t] = -1;            // sentinel: forces flush at end
    __syncthreads();

    f32x4 acc = {0.f, 0.f, 0.f, 0.f};
    for (int i0 = 0; i0 < cnt; i0 += 8) {
        const int m = min(8, cnt - i0);
        f32x4 v[8];
        #pragma unroll
        for (int j = 0; j < 8; ++j) {
            if (j < m) {
                int r = ent[i0 + j] & 0xFFFF;
                v[j] = *reinterpret_cast<const f32x4*>(&flat[(size_t)r * D_DIM + t * 4]);
            }
        }
        #pragma unroll
        for (int j = 0; j < 8; ++j) {
            if (j < m) {
                acc[0] += v[j][0]; acc[1] += v[j][1];
                acc[2] += v[j][2]; acc[3] += v[j][3];
                int k = ent[i0 + j] >> 16;
                if ((ent[i0 + j + 1] >> 16) != k) {   // uniform branch
                    float* p = &dw[(size_t)k * D_DIM + t * 4];
                    atomicAdd(p + 0, acc[0]);
                    atomicAdd(p + 1, acc[1]);
                    atomicAdd(p + 2, acc[2]);
                    atomicAdd(p + 3, acc[3]);
                    acc = f32x4{0.f, 0.f, 0.f, 0.f};
                }
            }
        }
    }
}

// ---------------------------------------------------------------------------
// fused tail: blocks [0,nfin) = finalize per code (new_ema_w/new_emb/new_count);
// blocks [nfin,..) = per-row gather, recomputing nw/nc from dw directly.
__global__ __launch_bounds__(256)
void tail_kernel(const float* __restrict__ codebook,
                 const float* __restrict__ ema_count, const float* __restrict__ ema_w,
                 const float* __restrict__ counts, const float* __restrict__ dw,
                 const int* __restrict__ indices,
                 float* __restrict__ new_emb, float* __restrict__ new_count,
                 float* __restrict__ new_ema_w,
                 float* __restrict__ zq, float* __restrict__ zqb, int nfin) {
    int b = blockIdx.x;
    if (b < nfin) {
        int gid = b * 256 + threadIdx.x;   // K*D/4 domain
        int k = gid >> 7;
        int d = (gid & 127) * 4;
        float nc = DECAY * ema_count[k] + OMD * counts[k];
        size_t off = (size_t)k * D_DIM + d;
        f32x4 w  = *reinterpret_cast<const f32x4*>(&ema_w[off]);
        f32x4 dv = *reinterpret_cast<const f32x4*>(&dw[off]);
        f32x4 nw, ne;
        float inv = 1.0f / nc;
        #pragma unroll
        for (int j = 0; j < 4; ++j) {
            nw[j] = DECAY * w[j] + OMD * dv[j];
            ne[j] = nw[j] * inv;
        }
        *reinterpret_cast<f32x4*>(&new_ema_w[off]) = nw;
        *reinterpret_cast<f32x4*>(&new_emb[off])   = ne;
        if ((gid & 127) == 0) new_count[k] = nc;
    } else {
        int gid = (b - nfin) * 256 + threadIdx.x;   // N*D/4 domain
        int r = gid >> 7;
        int d = (gid & 127) * 4;
        int k = indices[r];
        size_t src = (size_t)k * D_DIM + d;
        size_t dst = (size_t)r * D_DIM + d;
        float nc = DECAY * ema_count[k] + OMD * counts[k];
        float inv = 1.0f / nc;
        f32x4 w  = *reinterpret_cast<const f32x4*>(&ema_w[src]);
        f32x4 dv = *reinterpret_cast<const f32x4*>(&dw[src]);
        f32x4 zb;
        #pragma unroll
        for (int j = 0; j < 4; ++j) zb[j] = (DECAY * w[j] + OMD * dv[j]) * inv;
        *reinterpret_cast<f32x4*>(&zqb[dst]) = zb;
        *reinterpret_cast<f32x4*>(&zq[dst])  = *reinterpret_cast<const f32x4*>(&codebook[src]);
    }
}

// ---------------------------------------------------------------------------
extern "C" void kernel_launch(void* const* d_in, const int* in_sizes, int n_in,
                              void* d_out, int out_size, void* d_ws, size_t ws_size,
                              hipStream_t stream) {
    const float* z_e_x     = (const float*)d_in[0];
    const float* codebook  = (const float*)d_in[1];
    const float* ema_count = (const float*)d_in[2];
    const float* ema_w     = (const float*)d_in[3];

    const int N = in_sizes[0] / D_DIM;   // 16384

    float* out = (float*)d_out;
    float* z_q_x     = out;
    float* z_q_x_bar = z_q_x + (size_t)N * D_DIM;
    float* new_emb   = z_q_x_bar + (size_t)N * D_DIM;
    float* new_count = new_emb + (size_t)K_CODES * D_DIM;
    float* new_ema_w = new_count + K_CODES;

    // Ah/Al (N*D f16 each = 32 MB total) live in the z_q_x_bar output region:
    // exactly N*D*4 bytes, not written until the final tail gather.
    _Float16* Ahp = (_Float16*)z_q_x_bar;
    _Float16* Alp = Ahp + (size_t)N * D_DIM;

    // workspace: indices | cbsqr | minkey | counts | hist | bh/bl(=dw) | offs | cursor | packed
    char* ws = (char*)d_ws;
    int*   indices = (int*)ws;                                   // N ints
    float* cbsqr   = (float*)(ws + (size_t)N * 4);               // K
    u64*   minkey  = (u64*)(cbsqr + K_CODES);                    // N u64 (8B-aligned)
    float* counts  = (float*)(minkey + N);                       // K
    int*   hist    = (int*)(counts + K_CODES);                   // K ints
    _Float16* bh   = (_Float16*)(hist + K_CODES);                // K*D f16
    _Float16* bl   = bh + (size_t)K_CODES * D_DIM;               // K*D f16
    float* dw      = (float*)bh;                                 // K*D f32 (alias)
    int*   offs    = (int*)(bl + (size_t)K_CODES * D_DIM);       // K+1 ints
    int*   cursor  = offs + K_CODES + 1;                         // K ints
    int*   packed  = cursor + K_CODES;                           // N ints

    const int nA = (N * D_DIM / 8) / 256;        // splitA blocks (4096)
    const int nB = K_CODES / 4;                  // B-prep blocks (256)
    const int nI = N / 256;                      // minkey-init blocks (64)
    const int nH = K_CODES / 256;                // hist-zero blocks (4)
    prepsplit_kernel<<<nA + nB + nI + nH, 256, 0, stream>>>(
        z_e_x, codebook, cbsqr, minkey, hist, Ahp, Alp, bh, bl, nA, nB, nI);

    dim3 g_argmin(N / BM, K_CODES / BN);   // (128, 8)
    argmin_mfma<<<g_argmin, 256, 0, stream>>>(Ahp, Alp, bh, bl, cbsqr, minkey);

    decode_kernel<<<(N + 255) / 256, 256, 0, stream>>>(minkey, indices, hist, N);
    scan_kernel<<<1, 256, 0, stream>>>(hist, counts, offs, cursor);

    const int nzero = (K_CODES * D_DIM / 4) / 256;   // 512 zero blocks
    zeroscatter_kernel<<<nzero + (N + 255) / 256, 256, 0, stream>>>(
        indices, cursor, packed, (float4*)dw, N, nzero);

    chunksum_kernel<<<(N + CHUNK - 1) / CHUNK, 128, 0, stream>>>(z_e_x, packed, dw, N);

    const int nfin = (K_CODES * D_DIM / 4) / 256;    // 512 finalize blocks
    tail_kernel<<<nfin + (N * D_DIM / 4) / 256, 256, 0, stream>>>(
        codebook, ema_count, ema_w, counts, dw, indices,
        new_emb, new_count, new_ema_w, z_q_x, z_q_x_bar, nfin);
}